// Round 11
// baseline (285.195 us; speedup 1.0000x reference)
//
#include <hip/hip_runtime.h>
#include <math.h>

// SatLossEvaluator R11 — bucket_accum restructured as function-multisplit +
// atomic-free per-function register reduction (1 LDS atomic slot per record
// instead of 2; exact float math, fixed-point D/T packing removed).
// bin_edges unchanged from R10 (at its atomic+latency floor).
//
// record u32 = (f_local:11 << 20) | (ef_sign:1 << 19) | (var_idx:19)
// bucket = fun_idx >> 11 (S_FUN=2048, K<=1024)
// ws: [gcounts K u32][partials K double][vpdl V float2][records K*cap u32]

#define THREADS 256
#define S_LOG2  11
#define S_FUN   2048
#define K_MAX   1024
#define TILE    8192
#define ITEMS   (TILE / THREADS)   // 32 records per thread (bin_edges)
#define QUADS   (ITEMS / 4)
#define SCAP    9216               // accum staging (mean 8188, +11 sigma)
#define MAXQ    (SCAP / 4 / THREADS)   // 9 vec4 loads per thread

typedef unsigned uint4n __attribute__((ext_vector_type(4)));
typedef float    float4n __attribute__((ext_vector_type(4)));
typedef float    float2n __attribute__((ext_vector_type(2)));

__global__ void __launch_bounds__(THREADS)
bin_edges(const int* __restrict__ gmap,      // [2,E]
          const float* __restrict__ ef,
          const float* __restrict__ vp,
          const float* __restrict__ dl,
          float2n* __restrict__ vpdl,
          unsigned* __restrict__ gcounts,    // K
          unsigned* __restrict__ records,    // K * cap
          int E, int V, int K, int cap, int tiles) {
    // LDS = 4KB + 4KB + 32KB = 40960 B exactly -> 4 blocks/CU
    __shared__ unsigned hist[K_MAX];   // counts -> (gbase - offs) delta
    __shared__ unsigned offs[K_MAX];   // exclusive scan
    __shared__ unsigned staging[TILE]; // first 4 words double as scan scratch

    if (blockIdx.x >= (unsigned)tiles) {
        // ---- fused table build: vpdl[i] = (vp[i], dl[i]) ----
        int q = (blockIdx.x - tiles) * THREADS + threadIdx.x;
        if (q * 4 + 3 < V) {
            float4n p4 = __builtin_nontemporal_load((const float4n*)vp + q);
            float4n d4 = __builtin_nontemporal_load((const float4n*)dl + q);
            #pragma unroll
            for (int c = 0; c < 4; ++c) {
                float2n t; t.x = p4[c]; t.y = d4[c];
                __builtin_nontemporal_store(t, vpdl + q * 4 + c);
            }
        } else {
            for (int c = 0; c < 4; ++c) {
                int i = q * 4 + c;
                if (i < V) { float2n t; t.x = vp[i]; t.y = dl[i]; vpdl[i] = t; }
            }
        }
        return;
    }

    unsigned rec[ITEMS];
    unsigned bp[ITEMS];   // (bucket:10 << 13) | pos:13 ; 0xFFFFFFFF = invalid

    int base = blockIdx.x * TILE;
    int n = min(TILE, E - base);
    bool full = (n == TILE);

    for (int i = threadIdx.x; i < K; i += THREADS) hist[i] = 0u;
    __syncthreads();

    const unsigned* funp = (const unsigned*)(gmap + E) + base;
    const unsigned* varp = (const unsigned*)gmap + base;
    const float*    efp  = ef + base;

    #pragma unroll
    for (int k = 0; k < QUADS; ++k) {
        int q = k * THREADS + threadIdx.x;
        if (full || q * 4 + 3 < n) {
            uint4n  f4 = __builtin_nontemporal_load((const uint4n*)funp + q);
            uint4n  v4 = __builtin_nontemporal_load((const uint4n*)varp + q);
            float4n e4 = __builtin_nontemporal_load((const float4n*)efp + q);
            #pragma unroll
            for (int c = 0; c < 4; ++c) {
                unsigned f = f4[c], v = v4[c];
                float    e = e4[c];
                unsigned b = f >> S_LOG2;
                rec[k * 4 + c] = ((f & (S_FUN - 1)) << 20) |
                                 ((e < 0.0f ? 1u : 0u) << 19) | v;
                unsigned pos = atomicAdd(&hist[b], 1u);
                bp[k * 4 + c] = (b << 13) | pos;
            }
        } else {
            #pragma unroll
            for (int c = 0; c < 4; ++c) {
                int j = q * 4 + c;
                if (j < n) {
                    unsigned f = funp[j], v = varp[j];
                    float    e = efp[j];
                    unsigned b = f >> S_LOG2;
                    rec[k * 4 + c] = ((f & (S_FUN - 1)) << 20) |
                                     ((e < 0.0f ? 1u : 0u) << 19) | v;
                    unsigned pos = atomicAdd(&hist[b], 1u);
                    bp[k * 4 + c] = (b << 13) | pos;
                } else bp[k * 4 + c] = 0xFFFFFFFFu;
            }
        }
    }
    __syncthreads();

    // exclusive scan hist -> offs (wred scratch aliased into staging)
    {
        unsigned* wred = staging;
        int t4 = threadIdx.x * 4;
        unsigned a0 = (t4 + 0 < K) ? hist[t4 + 0] : 0u;
        unsigned a1 = (t4 + 1 < K) ? hist[t4 + 1] : 0u;
        unsigned a2 = (t4 + 2 < K) ? hist[t4 + 2] : 0u;
        unsigned a3 = (t4 + 3 < K) ? hist[t4 + 3] : 0u;
        unsigned s = a0 + a1 + a2 + a3;
        unsigned sc = s;
        int lane = threadIdx.x & 63, wid = threadIdx.x >> 6;
        #pragma unroll
        for (int d = 1; d < 64; d <<= 1) {
            unsigned t = __shfl_up(sc, d, 64);
            if (lane >= d) sc += t;
        }
        if (lane == 63) wred[wid] = sc;
        __syncthreads();
        unsigned wb = 0;
        for (int w = 0; w < wid; ++w) wb += wred[w];
        unsigned ex = wb + sc - s;
        if (t4 + 0 < K) { offs[t4 + 0] = ex; ex += a0; }
        if (t4 + 1 < K) { offs[t4 + 1] = ex; ex += a1; }
        if (t4 + 2 < K) { offs[t4 + 2] = ex; ex += a2; }
        if (t4 + 3 < K) { offs[t4 + 3] = ex; ex += a3; }
    }
    __syncthreads();

    // reserve global runs; overwrite hist in place with (gbase - offs) delta
    for (int b = threadIdx.x; b < K; b += THREADS) {
        unsigned h = hist[b];
        if (h) hist[b] = atomicAdd(&gcounts[b], h) - offs[b];
    }
    __syncthreads();

    // scatter records bucket-contiguously into staging
    #pragma unroll
    for (int k = 0; k < ITEMS; ++k) {
        unsigned m = bp[k];
        if (m != 0xFFFFFFFFu)
            staging[offs[m >> 13] + (m & 0x1FFFu)] = rec[k];
    }
    __syncthreads();

    // copy out: dst = delta[lo] + j ; bucket lo via binary search on offs
    for (int j = threadIdx.x; j < n; j += THREADS) {
        unsigned r = staging[j];
        int lo = 0, hi = K - 1;
        while (lo < hi) {
            int mid = (lo + hi + 1) >> 1;
            if (offs[mid] <= (unsigned)j) lo = mid; else hi = mid - 1;
        }
        unsigned dst = hist[lo] + (unsigned)j;   // gbase - offs + j
        if (dst < (unsigned)cap)                 // drop-guard (never hit)
            __builtin_nontemporal_store(r, &records[(size_t)lo * cap + dst]);
    }
}

// bucket_accum R11: function-multisplit (1 atomic/record) + atomic-free
// per-function register reduction + fused loss epilogue.
__global__ void __launch_bounds__(THREADS)
bucket_accum(const float2n* __restrict__ vpdl,
             const unsigned* __restrict__ gcounts,
             const unsigned* __restrict__ records,
             const float* __restrict__ gs,
             const float* __restrict__ mc,
             const float* __restrict__ eps_p,
             const int* __restrict__ ls_p,
             double* __restrict__ partials,
             int F, int cap) {
    __shared__ unsigned fhist[S_FUN];   // per-function counts (kept intact)
    __shared__ unsigned foffs[S_FUN];   // exclusive scan
    __shared__ unsigned stag[SCAP];     // records sorted by f_local
    __shared__ unsigned wred[THREADS / 64];
    __shared__ float red[THREADS / 64];

    int b = blockIdx.x;
    for (int i = threadIdx.x; i < S_FUN; i += THREADS) fhist[i] = 0u;
    __syncthreads();

    unsigned cnt = gcounts[b];
    if (cnt > (unsigned)cap) cnt = (unsigned)cap;
    if (cnt > SCAP) cnt = SCAP;                    // guard (never hit)
    const unsigned* rec = records + (size_t)b * cap;

    // phase 1: load records into registers, pos-grab per f_local
    uint4n r4[MAXQ];
    unsigned ps[MAXQ * 4];
    unsigned cnt4 = cnt >> 2;
    #pragma unroll
    for (int k = 0; k < MAXQ; ++k) {
        unsigned q = threadIdx.x + k * THREADS;
        if (q < cnt4) {
            r4[k] = __builtin_nontemporal_load((const uint4n*)rec + q);
            #pragma unroll
            for (int c = 0; c < 4; ++c)
                ps[k * 4 + c] = atomicAdd(&fhist[r4[k][c] >> 20], 1u);
        }
    }
    unsigned tr = 0u, tp = 0u; bool thave = false;
    for (unsigned j = (cnt4 << 2) + threadIdx.x; j < cnt; j += THREADS) {
        tr = rec[j];
        tp = atomicAdd(&fhist[tr >> 20], 1u);
        thave = true;
    }
    __syncthreads();

    // exclusive scan fhist -> foffs (8 entries per thread)
    {
        int t8 = threadIdx.x * 8;
        unsigned a[8], s = 0;
        #pragma unroll
        for (int c = 0; c < 8; ++c) { a[c] = fhist[t8 + c]; s += a[c]; }
        unsigned sc = s;
        int lane = threadIdx.x & 63, wid = threadIdx.x >> 6;
        #pragma unroll
        for (int d = 1; d < 64; d <<= 1) {
            unsigned t = __shfl_up(sc, d, 64);
            if (lane >= d) sc += t;
        }
        if (lane == 63) wred[wid] = sc;
        __syncthreads();
        unsigned wb = 0;
        for (int w = 0; w < wid; ++w) wb += wred[w];
        unsigned ex = wb + sc - s;
        #pragma unroll
        for (int c = 0; c < 8; ++c) { foffs[t8 + c] = ex; ex += a[c]; }
    }
    __syncthreads();

    // phase 2: scatter records function-contiguously
    #pragma unroll
    for (int k = 0; k < MAXQ; ++k) {
        unsigned q = threadIdx.x + k * THREADS;
        if (q < cnt4) {
            #pragma unroll
            for (int c = 0; c < 4; ++c) {
                unsigned r = r4[k][c];
                stag[foffs[r >> 20] + ps[k * 4 + c]] = r;
            }
        }
    }
    if (thave) stag[foffs[tr >> 20] + tp] = tr;
    __syncthreads();

    // phase 3: per-function atomic-free reduction + fused loss (exact float)
    float coeff = fminf(sqrtf(gs[0]), mc[0]);   // ALPHA = 0.5
    float epsv = eps_p[0];
    int   ls   = ls_p[0];
    float local = 0.0f;
    int fbase = b << S_LOG2;
    for (int fl = threadIdx.x; fl < S_FUN; fl += THREADS) {
        int fg = fbase + fl;
        if (fg >= F) break;
        unsigned start = foffs[fl];
        unsigned deg   = fhist[fl];
        float N = 0.0f, D = 0.0f, T = 0.0f;
        for (unsigned i = 0; i < deg; ++i) {
            unsigned r = stag[start + i];
            float e = (r >> 19) & 1u ? -1.0f : 1.0f;
            float2n t = vpdl[r & 0x7FFFFu];
            float ev = e * t.x + (1.0f - e) * 0.5f;
            float w = __expf(coeff * ev);
            N += w * ev; D += w; T += e * t.y;
        }
        float cv = D / fmaxf(N, epsv);
        float d = cv - 1.0f;
        float p = 1.0f;
        for (int k = 0; k < ls; ++k) p *= d;   // handles d<0 (ls odd)
        cv = T * (1.0f + p);
        local += __logf(fmaxf(cv, epsv));
    }
    #pragma unroll
    for (int off = 32; off > 0; off >>= 1)
        local += __shfl_down(local, off, 64);
    int lane = threadIdx.x & 63, wid = threadIdx.x >> 6;
    if (lane == 0) red[wid] = local;
    __syncthreads();
    if (threadIdx.x == 0) {
        float s = 0.0f;
        #pragma unroll
        for (int w = 0; w < THREADS / 64; ++w) s += red[w];
        partials[b] = (double)s;
    }
}

__global__ void final_reduce(const double* __restrict__ partials, int nparts,
                             float* __restrict__ out, int F) {
    __shared__ double sm[THREADS];
    double local = 0.0;
    for (int i = threadIdx.x; i < nparts; i += blockDim.x) local += partials[i];
    sm[threadIdx.x] = local;
    __syncthreads();
    for (int s = blockDim.x / 2; s > 0; s >>= 1) {
        if ((int)threadIdx.x < s) sm[threadIdx.x] += sm[threadIdx.x + s];
        __syncthreads();
    }
    if (threadIdx.x == 0) out[0] = (float)(sm[0] / (double)F);
}

extern "C" void kernel_launch(void* const* d_in, const int* in_sizes, int n_in,
                              void* d_out, int out_size, void* d_ws, size_t ws_size,
                              hipStream_t stream) {
    const float* vp   = (const float*)d_in[0];
    const float* dl   = (const float*)d_in[1];
    const int*   gmap = (const int*)d_in[3];
    const float* ef   = (const float*)d_in[6];
    const float* gs   = (const float*)d_in[8];
    const float* eps  = (const float*)d_in[9];
    const float* mc   = (const float*)d_in[10];
    const int*   ls   = (const int*)d_in[11];

    const int V = in_sizes[0];
    const int F = in_sizes[5];
    const int E = in_sizes[6];
    const int K = (F + S_FUN - 1) / S_FUN;   // 977 at F=2M

    size_t off = ((size_t)K * sizeof(unsigned) + 15) & ~(size_t)15;
    unsigned* gcounts = (unsigned*)d_ws;
    double* partials = (double*)((char*)d_ws + off);
    off = (off + (size_t)K * sizeof(double) + 15) & ~(size_t)15;
    float2n* vpdl = (float2n*)((char*)d_ws + off);
    off = (off + (size_t)V * sizeof(float2n) + 15) & ~(size_t)15;

    long long cap = (ws_size > off)
        ? (long long)((ws_size - off) / ((size_t)K * sizeof(unsigned))) : 4;
    if (cap > SCAP) cap = SCAP;     // mean E/K ~8.2K, +11 sigma headroom
    cap &= ~3LL;
    if (cap < 4) cap = 4;

    unsigned* records = (unsigned*)((char*)d_ws + off);

    hipMemsetAsync(gcounts, 0, (size_t)K * sizeof(unsigned), stream);

    int tiles = (E + TILE - 1) / TILE;
    int fblocks = (V + THREADS * 4 - 1) / (THREADS * 4);
    bin_edges<<<tiles + fblocks, THREADS, 0, stream>>>(
        gmap, ef, vp, dl, vpdl, gcounts, records, E, V, K, (int)cap, tiles);

    bucket_accum<<<K, THREADS, 0, stream>>>(vpdl, gcounts, records,
                                            gs, mc, eps, ls, partials,
                                            F, (int)cap);

    final_reduce<<<1, THREADS, 0, stream>>>(partials, K, (float*)d_out, F);
}